// Round 1
// baseline (994.172 us; speedup 1.0000x reference)
//
#include <hip/hip_runtime.h>

#define NA 250000
#define NB 500000
#define NG 50000
#define DD 64
#define EA_N 1000000
#define EG_N 500000
#define FTC 320  // 5*64

// ---------------- helpers ----------------

__device__ __forceinline__ unsigned float_to_key(float f) {
    unsigned u = __float_as_uint(f);
    return (u & 0x80000000u) ? ~u : (u | 0x80000000u);
}
__device__ __forceinline__ float key_to_float(unsigned k) {
    unsigned u = (k & 0x80000000u) ? (k & 0x7FFFFFFFu) : ~k;
    return __uint_as_float(u);
}

// ---------------- kernels ----------------

__global__ void copy_f4_kernel(const float4* __restrict__ src,
                               float4* __restrict__ dst, long long n4) {
    long long i = (long long)blockIdx.x * blockDim.x + threadIdx.x;
    long long stride = (long long)gridDim.x * blockDim.x;
    for (; i < n4; i += stride) dst[i] = src[i];
}

// ft[b][0:64] = bond[b]; ft[b][64:320] = 0 (0.0f sums AND minimum max-key)
__global__ void init_ft_kernel(const float4* __restrict__ bond,
                               float4* __restrict__ ft) {
    const long long n4 = (long long)NB * (FTC / 4);  // 80 float4 per row
    long long i = (long long)blockIdx.x * blockDim.x + threadIdx.x;
    long long stride = (long long)gridDim.x * blockDim.x;
    for (; i < n4; i += stride) {
        long long b = i / 80;
        int c4 = (int)(i - b * 80);
        float4 v = make_float4(0.f, 0.f, 0.f, 0.f);
        if (c4 < 16) v = bond[b * 16 + c4];
        ft[i] = v;
    }
}

// One thread per (edge, d). 64 consecutive threads share an edge.
__global__ void scatter_kernel(const float* __restrict__ src_ft,
                               const int* __restrict__ src_idx,
                               const int* __restrict__ dst_idx,
                               int n_edges,
                               float* __restrict__ ft,  // base of [NB,320]
                               int sum_col, int max_col,
                               int* __restrict__ cnt) {
    long long total = (long long)n_edges * 64;
    long long i = (long long)blockIdx.x * blockDim.x + threadIdx.x;
    long long stride = (long long)gridDim.x * blockDim.x;
    for (; i < total; i += stride) {
        int e = (int)(i >> 6);
        int d = (int)(i & 63);
        int s = src_idx[e];   // wave-uniform -> scalar load
        int b = dst_idx[e];
        float v = src_ft[(long long)s * DD + d];
        atomicAdd(&ft[(long long)b * FTC + sum_col + d], v);
        atomicMax((unsigned*)&ft[(long long)b * FTC + max_col + d],
                  float_to_key(v));
        if (d == 0) atomicAdd(&cnt[b], 1);
    }
}

// Convert sums -> means, decode max keys, zero-degree -> 0. Handles both etypes.
__global__ void finalize_kernel(float* __restrict__ ft,
                                const int* __restrict__ cnt_a,
                                const int* __restrict__ cnt_g) {
    long long total = (long long)NB * 64;
    long long i = (long long)blockIdx.x * blockDim.x + threadIdx.x;
    long long stride = (long long)gridDim.x * blockDim.x;
    for (; i < total; i += stride) {
        long long b = i >> 6;
        int d = (int)(i & 63);
        float* row = ft + b * FTC;

        int ca = cnt_a[b];  // wave-uniform
        float sa = row[64 + d];
        row[64 + d] = sa / fmaxf((float)ca, 1.0f);
        unsigned ka = __float_as_uint(row[128 + d]);
        row[128 + d] = (ca > 0) ? key_to_float(ka) : 0.0f;

        int cg = cnt_g[b];
        float sg = row[192 + d];
        row[192 + d] = sg / fmaxf((float)cg, 1.0f);
        unsigned kg = __float_as_uint(row[256 + d]);
        row[256 + d] = (cg > 0) ? key_to_float(kg) : 0.0f;
    }
}

// ---------------- launch ----------------

extern "C" void kernel_launch(void* const* d_in, const int* in_sizes, int n_in,
                              void* d_out, int out_size, void* d_ws, size_t ws_size,
                              hipStream_t stream) {
    const float* atom_ft   = (const float*)d_in[0];
    const float* bond_ft   = (const float*)d_in[1];
    const float* global_ft = (const float*)d_in[2];
    const int* a2b_src = (const int*)d_in[3];
    const int* a2b_dst = (const int*)d_in[4];
    const int* g2b_src = (const int*)d_in[5];
    const int* g2b_dst = (const int*)d_in[6];

    float* out = (float*)d_out;
    float* out_atom = out;                                   // [NA,64]
    float* out_ft   = out + (long long)NA * DD;              // [NB,320]
    float* out_glob = out_ft + (long long)NB * FTC;          // [NG,64]

    int* cnt_a = (int*)d_ws;        // [NB]
    int* cnt_g = cnt_a + NB;        // [NB]

    // zero the counts (poisoned to 0xAA before timing; we must re-init each call)
    hipMemsetAsync(d_ws, 0, 2 * (size_t)NB * sizeof(int), stream);

    const int BLK = 256;

    // pass-through copies
    copy_f4_kernel<<<4096, BLK, 0, stream>>>(
        (const float4*)atom_ft, (float4*)out_atom, (long long)NA * DD / 4);
    copy_f4_kernel<<<2048, BLK, 0, stream>>>(
        (const float4*)global_ft, (float4*)out_glob, (long long)NG * DD / 4);

    // ft init: bond cols + zeroed accumulator cols
    init_ft_kernel<<<8192, BLK, 0, stream>>>(
        (const float4*)bond_ft, (float4*)out_ft);

    // scatters
    scatter_kernel<<<8192, BLK, 0, stream>>>(
        atom_ft, a2b_src, a2b_dst, EA_N, out_ft, 64, 128, cnt_a);
    scatter_kernel<<<8192, BLK, 0, stream>>>(
        global_ft, g2b_src, g2b_dst, EG_N, out_ft, 192, 256, cnt_g);

    // finalize
    finalize_kernel<<<8192, BLK, 0, stream>>>(out_ft, cnt_a, cnt_g);
}

// Round 2
// 598.832 us; speedup vs baseline: 1.6602x; 1.6602x over previous
//
#include <hip/hip_runtime.h>

#define NA 250000
#define NB 500000
#define NG 50000
#define DD 64
#define EA_N 1000000
#define EG_N 500000
#define FTC 320           // 5*64
#define NSEG (2 * NB)     // segment counts: [0,NB) = a2b, [NB,2NB) = g2b
#define SCAN_BLK 1024
#define NSCAN_BLKS ((NSEG + SCAN_BLK - 1) / SCAN_BLK)  // 977 <= 1024

// ---------------- utility kernels ----------------

__global__ void copy_f4_kernel(const float4* __restrict__ src,
                               float4* __restrict__ dst, long long n4) {
    long long i = (long long)blockIdx.x * blockDim.x + threadIdx.x;
    long long stride = (long long)gridDim.x * blockDim.x;
    for (; i < n4; i += stride) dst[i] = src[i];
}

__global__ void zero_int_kernel(int* __restrict__ p, int n) {
    int i = blockIdx.x * blockDim.x + threadIdx.x;
    int stride = gridDim.x * blockDim.x;
    for (; i < n; i += stride) p[i] = 0;
}

// ---------------- CSR build ----------------

__global__ void count_kernel(const int* __restrict__ a2b_dst,
                             const int* __restrict__ g2b_dst,
                             int* __restrict__ cnt) {
    int i = blockIdx.x * blockDim.x + threadIdx.x;
    int stride = gridDim.x * blockDim.x;
    int total = EA_N + EG_N;
    for (; i < total; i += stride) {
        if (i < EA_N) atomicAdd(&cnt[a2b_dst[i]], 1);
        else          atomicAdd(&cnt[NB + g2b_dst[i - EA_N]], 1);
    }
}

__global__ void scan1_kernel(const int* __restrict__ cnt,
                             int* __restrict__ offs,
                             int* __restrict__ bsum) {
    __shared__ int sm[SCAN_BLK];
    int tid = threadIdx.x;
    int idx = blockIdx.x * SCAN_BLK + tid;
    int v = (idx < NSEG) ? cnt[idx] : 0;
    sm[tid] = v;
    __syncthreads();
    for (int off = 1; off < SCAN_BLK; off <<= 1) {
        int t = (tid >= off) ? sm[tid - off] : 0;
        __syncthreads();
        sm[tid] += t;
        __syncthreads();
    }
    if (idx < NSEG) offs[idx] = sm[tid] - v;          // exclusive within block
    if (tid == SCAN_BLK - 1) bsum[blockIdx.x] = sm[tid];
}

__global__ void scan2_kernel(int* __restrict__ bsum) {  // single block
    __shared__ int sm[SCAN_BLK];
    int tid = threadIdx.x;
    int v = (tid < NSCAN_BLKS) ? bsum[tid] : 0;
    sm[tid] = v;
    __syncthreads();
    for (int off = 1; off < SCAN_BLK; off <<= 1) {
        int t = (tid >= off) ? sm[tid - off] : 0;
        __syncthreads();
        sm[tid] += t;
        __syncthreads();
    }
    if (tid < NSCAN_BLKS) bsum[tid] = sm[tid] - v;    // exclusive
}

__global__ void scan3_kernel(int* __restrict__ offs,
                             const int* __restrict__ bsum,
                             int* __restrict__ cursor) {
    int idx = blockIdx.x * SCAN_BLK + threadIdx.x;
    if (idx < NSEG) {
        int o = offs[idx] + bsum[blockIdx.x];
        offs[idx] = o;
        cursor[idx] = o;
    }
    if (idx == 0) offs[NSEG] = EA_N + EG_N;
}

__global__ void fill_kernel(const int* __restrict__ a2b_src,
                            const int* __restrict__ a2b_dst,
                            const int* __restrict__ g2b_src,
                            const int* __restrict__ g2b_dst,
                            int* __restrict__ cursor,
                            int* __restrict__ esrc) {
    int i = blockIdx.x * blockDim.x + threadIdx.x;
    int stride = gridDim.x * blockDim.x;
    int total = EA_N + EG_N;
    for (; i < total; i += stride) {
        int b, s;
        if (i < EA_N) { b = a2b_dst[i];      s = a2b_src[i]; }
        else          { b = NB + g2b_dst[i - EA_N]; s = g2b_src[i - EA_N]; }
        int pos = atomicAdd(&cursor[b], 1);
        esrc[pos] = s;
    }
}

// ---------------- fused per-bond row writer ----------------
// One wave (64 lanes = 64 dims) per bond. Gathers are coalesced 256B reads.

__global__ __launch_bounds__(256) void bond_row_kernel(
    const float* __restrict__ bond, const float* __restrict__ atom,
    const float* __restrict__ glob, const int* __restrict__ offs,
    const int* __restrict__ esrc, float* __restrict__ ft) {
    int wave = (int)((blockIdx.x * blockDim.x + threadIdx.x) >> 6);
    int lane = threadIdx.x & 63;
    if (wave >= NB) return;
    long long b = wave;

    float bv = bond[b * DD + lane];

    int a0 = offs[b], a1 = offs[b + 1];
    float sum_a = 0.f, max_a = -INFINITY;
    for (int e = a0; e < a1; ++e) {
        int s = esrc[e];                              // wave-uniform
        float v = atom[(long long)s * DD + lane];     // coalesced 256B
        sum_a += v;
        max_a = fmaxf(max_a, v);
    }
    int dega = a1 - a0;
    float mean_a = dega ? sum_a / (float)dega : 0.f;
    if (!dega) max_a = 0.f;

    int g0 = offs[NB + b], g1 = offs[NB + b + 1];
    float sum_g = 0.f, max_g = -INFINITY;
    for (int e = g0; e < g1; ++e) {
        int s = esrc[e];
        float v = glob[(long long)s * DD + lane];
        sum_g += v;
        max_g = fmaxf(max_g, v);
    }
    int degg = g1 - g0;
    float mean_g = degg ? sum_g / (float)degg : 0.f;
    if (!degg) max_g = 0.f;

    float* row = ft + b * FTC;
    row[lane]       = bv;
    row[64  + lane] = mean_a;
    row[128 + lane] = max_a;
    row[192 + lane] = mean_g;
    row[256 + lane] = max_g;
}

// ---------------- launch ----------------

extern "C" void kernel_launch(void* const* d_in, const int* in_sizes, int n_in,
                              void* d_out, int out_size, void* d_ws, size_t ws_size,
                              hipStream_t stream) {
    const float* atom_ft   = (const float*)d_in[0];
    const float* bond_ft   = (const float*)d_in[1];
    const float* global_ft = (const float*)d_in[2];
    const int* a2b_src = (const int*)d_in[3];
    const int* a2b_dst = (const int*)d_in[4];
    const int* g2b_src = (const int*)d_in[5];
    const int* g2b_dst = (const int*)d_in[6];

    float* out = (float*)d_out;
    float* out_atom = out;                            // [NA,64]
    float* out_ft   = out + (long long)NA * DD;       // [NB,320]
    float* out_glob = out_ft + (long long)NB * FTC;   // [NG,64]

    // workspace layout (ints)
    int* ws      = (int*)d_ws;
    int* cnt     = ws;                   // NSEG
    int* offs    = ws + 1000000;         // NSEG+1
    int* cursor  = ws + 2000004;         // NSEG
    int* bsum    = ws + 3000004;         // SCAN_BLK
    int* esrc    = ws + 3001028;         // EA_N+EG_N = 1.5M
    // total ~18 MB

    const int BLK = 256;

    zero_int_kernel<<<2048, BLK, 0, stream>>>(cnt, NSEG);

    count_kernel<<<2048, BLK, 0, stream>>>(a2b_dst, g2b_dst, cnt);

    scan1_kernel<<<NSCAN_BLKS, SCAN_BLK, 0, stream>>>(cnt, offs, bsum);
    scan2_kernel<<<1, SCAN_BLK, 0, stream>>>(bsum);
    scan3_kernel<<<NSCAN_BLKS, SCAN_BLK, 0, stream>>>(offs, bsum, cursor);

    fill_kernel<<<2048, BLK, 0, stream>>>(a2b_src, a2b_dst, g2b_src, g2b_dst,
                                          cursor, esrc);

    // pass-through copies
    copy_f4_kernel<<<4096, BLK, 0, stream>>>(
        (const float4*)atom_ft, (float4*)out_atom, (long long)NA * DD / 4);
    copy_f4_kernel<<<2048, BLK, 0, stream>>>(
        (const float4*)global_ft, (float4*)out_glob, (long long)NG * DD / 4);

    // fused gather + reduce + concat row write
    bond_row_kernel<<<NB / 4, BLK, 0, stream>>>(
        bond_ft, atom_ft, global_ft, offs, esrc, out_ft);
}

// Round 3
// 437.520 us; speedup vs baseline: 2.2723x; 1.3687x over previous
//
#include <hip/hip_runtime.h>

#define NA 250000
#define NB 500000
#define NG 50000
#define DD 64
#define EA_N 1000000
#define EG_N 500000
#define FTC 320           // 5*64
#define NSEG (2 * NB)     // [0,NB) = a2b counts, [NB,2NB) = g2b counts
#define SCAN_BLK 1024
#define NSCAN_BLKS ((NSEG + SCAN_BLK - 1) / SCAN_BLK)  // 977

#define BOND_BLKS (NB / 16)   // 16 bonds per 256-thread block (16 lanes/bond)
#define COPYA_BLKS 1024
#define COPYG_BLKS 128

// ---------------- float4 helpers ----------------

__device__ __forceinline__ float4 f4add(float4 a, float4 b) {
    return make_float4(a.x + b.x, a.y + b.y, a.z + b.z, a.w + b.w);
}
__device__ __forceinline__ float4 f4max(float4 a, float4 b) {
    return make_float4(fmaxf(a.x, b.x), fmaxf(a.y, b.y),
                       fmaxf(a.z, b.z), fmaxf(a.w, b.w));
}
__device__ __forceinline__ float4 f4scale(float4 a, float s) {
    return make_float4(a.x * s, a.y * s, a.z * s, a.w * s);
}

// ---------------- CSR build ----------------

__global__ void zero_int_kernel(int* __restrict__ p, int n) {
    int i = blockIdx.x * blockDim.x + threadIdx.x;
    int stride = gridDim.x * blockDim.x;
    for (; i < n; i += stride) p[i] = 0;
}

__global__ void count_kernel(const int* __restrict__ a2b_dst,
                             const int* __restrict__ g2b_dst,
                             int* __restrict__ cnt) {
    int i = blockIdx.x * blockDim.x + threadIdx.x;
    int stride = gridDim.x * blockDim.x;
    int total = EA_N + EG_N;
    for (; i < total; i += stride) {
        if (i < EA_N) atomicAdd(&cnt[a2b_dst[i]], 1);
        else          atomicAdd(&cnt[NB + g2b_dst[i - EA_N]], 1);
    }
}

__global__ void scan1_kernel(const int* __restrict__ cnt,
                             int* __restrict__ offs,
                             int* __restrict__ bsum) {
    __shared__ int sm[SCAN_BLK];
    int tid = threadIdx.x;
    int idx = blockIdx.x * SCAN_BLK + tid;
    int v = (idx < NSEG) ? cnt[idx] : 0;
    sm[tid] = v;
    __syncthreads();
    for (int off = 1; off < SCAN_BLK; off <<= 1) {
        int t = (tid >= off) ? sm[tid - off] : 0;
        __syncthreads();
        sm[tid] += t;
        __syncthreads();
    }
    if (idx < NSEG) offs[idx] = sm[tid] - v;
    if (tid == SCAN_BLK - 1) bsum[blockIdx.x] = sm[tid];
}

__global__ void scan2_kernel(int* __restrict__ bsum) {
    __shared__ int sm[SCAN_BLK];
    int tid = threadIdx.x;
    int v = (tid < NSCAN_BLKS) ? bsum[tid] : 0;
    sm[tid] = v;
    __syncthreads();
    for (int off = 1; off < SCAN_BLK; off <<= 1) {
        int t = (tid >= off) ? sm[tid - off] : 0;
        __syncthreads();
        sm[tid] += t;
        __syncthreads();
    }
    if (tid < NSCAN_BLKS) bsum[tid] = sm[tid] - v;
}

__global__ void scan3_kernel(int* __restrict__ offs,
                             const int* __restrict__ bsum,
                             int* __restrict__ cursor) {
    int idx = blockIdx.x * SCAN_BLK + threadIdx.x;
    if (idx < NSEG) {
        int o = offs[idx] + bsum[blockIdx.x];
        offs[idx] = o;
        cursor[idx] = o;
    }
    if (idx == 0) offs[NSEG] = EA_N + EG_N;
}

__global__ void fill_kernel(const int* __restrict__ a2b_src,
                            const int* __restrict__ a2b_dst,
                            const int* __restrict__ g2b_src,
                            const int* __restrict__ g2b_dst,
                            int* __restrict__ cursor,
                            int* __restrict__ esrc) {
    int i = blockIdx.x * blockDim.x + threadIdx.x;
    int stride = gridDim.x * blockDim.x;
    int total = EA_N + EG_N;
    for (; i < total; i += stride) {
        int b, s;
        if (i < EA_N) { b = a2b_dst[i];           s = a2b_src[i]; }
        else          { b = NB + g2b_dst[i - EA_N]; s = g2b_src[i - EA_N]; }
        int pos = atomicAdd(&cursor[b], 1);
        esrc[pos] = s;
    }
}

// ---------------- fused mega kernel ----------------
// blocks [0, BOND_BLKS): 16 bonds/block, 16 lanes (float4) per bond.
// blocks [BOND_BLKS, +COPYA_BLKS): atom pass-through copy.
// remaining blocks: global pass-through copy.

__global__ __launch_bounds__(256) void mega_kernel(
    const float4* __restrict__ bond4, const float4* __restrict__ atom4,
    const float4* __restrict__ glob4, const int* __restrict__ offs,
    const int* __restrict__ esrc, float4* __restrict__ ft4,
    float4* __restrict__ out_atom4, float4* __restrict__ out_glob4) {
    int bid = blockIdx.x;

    if (bid < BOND_BLKS) {
        long long b = (long long)bid * 16 + (threadIdx.x >> 4);
        int q = threadIdx.x & 15;          // float4 slot within the row
        int gbase = threadIdx.x & 48;      // group base lane within the wave

        float4 bv = bond4[b * 16 + q];

        // ---- a2b: mean/max over atom neighbors ----
        int a0 = offs[b], a1 = offs[b + 1];
        float4 sa = make_float4(0.f, 0.f, 0.f, 0.f);
        float4 xa = make_float4(-INFINITY, -INFINITY, -INFINITY, -INFINITY);
        for (int base = a0; base < a1; base += 16) {
            int my_e = base + q;
            int my_s = (my_e < a1) ? esrc[my_e] : 0;
            int n = min(16, a1 - base);
            for (int j = 0; j < n; ++j) {
                int s = __shfl(my_s, gbase + j, 64);
                float4 v = atom4[(long long)s * 16 + q];
                sa = f4add(sa, v);
                xa = f4max(xa, v);
            }
        }
        int dega = a1 - a0;
        float4 ma = f4scale(sa, dega ? 1.f / (float)dega : 0.f);
        if (!dega) xa = make_float4(0.f, 0.f, 0.f, 0.f);

        // ---- g2b: mean/max over global neighbors ----
        int g0 = offs[NB + b], g1 = offs[NB + b + 1];
        float4 sg = make_float4(0.f, 0.f, 0.f, 0.f);
        float4 xg = make_float4(-INFINITY, -INFINITY, -INFINITY, -INFINITY);
        for (int base = g0; base < g1; base += 16) {
            int my_e = base + q;
            int my_s = (my_e < g1) ? esrc[my_e] : 0;
            int n = min(16, g1 - base);
            for (int j = 0; j < n; ++j) {
                int s = __shfl(my_s, gbase + j, 64);
                float4 v = glob4[(long long)s * 16 + q];
                sg = f4add(sg, v);
                xg = f4max(xg, v);
            }
        }
        int degg = g1 - g0;
        float4 mg = f4scale(sg, degg ? 1.f / (float)degg : 0.f);
        if (!degg) xg = make_float4(0.f, 0.f, 0.f, 0.f);

        // ---- write the 320-col row (80 float4) ----
        float4* row = ft4 + b * 80;
        row[q]      = bv;
        row[16 + q] = ma;
        row[32 + q] = xa;
        row[48 + q] = mg;
        row[64 + q] = xg;
    } else if (bid < BOND_BLKS + COPYA_BLKS) {
        long long n4 = (long long)NA * DD / 4;
        long long i = (long long)(bid - BOND_BLKS) * 256 + threadIdx.x;
        long long stride = (long long)COPYA_BLKS * 256;
        for (; i < n4; i += stride) out_atom4[i] = atom4[i];
    } else {
        long long n4 = (long long)NG * DD / 4;
        long long i = (long long)(bid - BOND_BLKS - COPYA_BLKS) * 256 + threadIdx.x;
        long long stride = (long long)COPYG_BLKS * 256;
        for (; i < n4; i += stride) out_glob4[i] = glob4[i];
    }
}

// ---------------- launch ----------------

extern "C" void kernel_launch(void* const* d_in, const int* in_sizes, int n_in,
                              void* d_out, int out_size, void* d_ws, size_t ws_size,
                              hipStream_t stream) {
    const float* atom_ft   = (const float*)d_in[0];
    const float* bond_ft   = (const float*)d_in[1];
    const float* global_ft = (const float*)d_in[2];
    const int* a2b_src = (const int*)d_in[3];
    const int* a2b_dst = (const int*)d_in[4];
    const int* g2b_src = (const int*)d_in[5];
    const int* g2b_dst = (const int*)d_in[6];

    float* out = (float*)d_out;
    float* out_atom = out;                            // [NA,64]
    float* out_ft   = out + (long long)NA * DD;       // [NB,320]
    float* out_glob = out_ft + (long long)NB * FTC;   // [NG,64]

    int* ws      = (int*)d_ws;
    int* cnt     = ws;                   // NSEG
    int* offs    = ws + 1000000;         // NSEG+1
    int* cursor  = ws + 2000004;         // NSEG
    int* bsum    = ws + 3000004;         // SCAN_BLK
    int* esrc    = ws + 3001028;         // EA_N+EG_N

    const int BLK = 256;

    zero_int_kernel<<<2048, BLK, 0, stream>>>(cnt, NSEG);
    count_kernel<<<2048, BLK, 0, stream>>>(a2b_dst, g2b_dst, cnt);
    scan1_kernel<<<NSCAN_BLKS, SCAN_BLK, 0, stream>>>(cnt, offs, bsum);
    scan2_kernel<<<1, SCAN_BLK, 0, stream>>>(bsum);
    scan3_kernel<<<NSCAN_BLKS, SCAN_BLK, 0, stream>>>(offs, bsum, cursor);
    fill_kernel<<<2048, BLK, 0, stream>>>(a2b_src, a2b_dst, g2b_src, g2b_dst,
                                          cursor, esrc);

    mega_kernel<<<BOND_BLKS + COPYA_BLKS + COPYG_BLKS, BLK, 0, stream>>>(
        (const float4*)bond_ft, (const float4*)atom_ft,
        (const float4*)global_ft, offs, esrc, (float4*)out_ft,
        (float4*)out_atom, (float4*)out_glob);
}

// Round 5
// 390.685 us; speedup vs baseline: 2.5447x; 1.1199x over previous
//
#include <hip/hip_runtime.h>

#define NA 250000
#define NB 500000
#define NG 50000
#define DD 64
#define EA_N 1000000
#define EG_N 500000
#define FTC 320           // 5*64
#define NSEG (2 * NB)     // [0,NB) = a2b counts, [NB,2NB) = g2b counts
#define SCAN_BLK 1024
#define NSCAN_BLKS ((NSEG + SCAN_BLK - 1) / SCAN_BLK)  // 977

#define BOND_BLKS (NB / 16)   // 16 bonds per 256-thread block (16 lanes/bond)
#define COPYA_BLKS 1024
#define COPYG_BLKS 128

// native clang vector type — required by __builtin_nontemporal_*
typedef float vf4 __attribute__((ext_vector_type(4)));

// ---------------- float4 helpers ----------------

__device__ __forceinline__ float4 f4add(float4 a, float4 b) {
    return make_float4(a.x + b.x, a.y + b.y, a.z + b.z, a.w + b.w);
}
__device__ __forceinline__ float4 f4max(float4 a, float4 b) {
    return make_float4(fmaxf(a.x, b.x), fmaxf(a.y, b.y),
                       fmaxf(a.z, b.z), fmaxf(a.w, b.w));
}
__device__ __forceinline__ float4 f4scale(float4 a, float s) {
    return make_float4(a.x * s, a.y * s, a.z * s, a.w * s);
}
__device__ __forceinline__ float4 ntload4(const float4* p) {
    vf4 v = __builtin_nontemporal_load((const vf4*)p);
    return make_float4(v.x, v.y, v.z, v.w);
}
__device__ __forceinline__ void ntstore4(float4 a, float4* p) {
    vf4 v = {a.x, a.y, a.z, a.w};
    __builtin_nontemporal_store(v, (vf4*)p);
}

// ---------------- CSR build ----------------

__global__ void count_kernel(const int4* __restrict__ a2b_dst4,
                             const int4* __restrict__ g2b_dst4,
                             int* __restrict__ cnt) {
    int i = blockIdx.x * blockDim.x + threadIdx.x;
    int stride = gridDim.x * blockDim.x;
    const int totalA = EA_N / 4;
    const int total = (EA_N + EG_N) / 4;
    for (; i < total; i += stride) {
        if (i < totalA) {
            int4 d = a2b_dst4[i];
            atomicAdd(&cnt[d.x], 1);
            atomicAdd(&cnt[d.y], 1);
            atomicAdd(&cnt[d.z], 1);
            atomicAdd(&cnt[d.w], 1);
        } else {
            int4 d = g2b_dst4[i - totalA];
            atomicAdd(&cnt[NB + d.x], 1);
            atomicAdd(&cnt[NB + d.y], 1);
            atomicAdd(&cnt[NB + d.z], 1);
            atomicAdd(&cnt[NB + d.w], 1);
        }
    }
}

__global__ void scan1_kernel(const int* __restrict__ cnt,
                             int* __restrict__ offs,
                             int* __restrict__ bsum) {
    __shared__ int sm[SCAN_BLK];
    int tid = threadIdx.x;
    int idx = blockIdx.x * SCAN_BLK + tid;
    int v = (idx < NSEG) ? cnt[idx] : 0;
    sm[tid] = v;
    __syncthreads();
    for (int off = 1; off < SCAN_BLK; off <<= 1) {
        int t = (tid >= off) ? sm[tid - off] : 0;
        __syncthreads();
        sm[tid] += t;
        __syncthreads();
    }
    if (idx < NSEG) offs[idx] = sm[tid] - v;
    if (tid == SCAN_BLK - 1) bsum[blockIdx.x] = sm[tid];
}

__global__ void scan2_kernel(int* __restrict__ bsum) {
    __shared__ int sm[SCAN_BLK];
    int tid = threadIdx.x;
    int v = (tid < NSCAN_BLKS) ? bsum[tid] : 0;
    sm[tid] = v;
    __syncthreads();
    for (int off = 1; off < SCAN_BLK; off <<= 1) {
        int t = (tid >= off) ? sm[tid - off] : 0;
        __syncthreads();
        sm[tid] += t;
        __syncthreads();
    }
    if (tid < NSCAN_BLKS) bsum[tid] = sm[tid] - v;
}

__global__ void scan3_kernel(int* __restrict__ offs,
                             const int* __restrict__ bsum,
                             int* __restrict__ cursor) {
    int idx = blockIdx.x * SCAN_BLK + threadIdx.x;
    if (idx < NSEG) {
        int o = offs[idx] + bsum[blockIdx.x];
        offs[idx] = o;
        cursor[idx] = o;
    }
    if (idx == 0) offs[NSEG] = EA_N + EG_N;
}

__global__ void fill_kernel(const int4* __restrict__ a2b_src4,
                            const int4* __restrict__ a2b_dst4,
                            const int4* __restrict__ g2b_src4,
                            const int4* __restrict__ g2b_dst4,
                            int* __restrict__ cursor,
                            int* __restrict__ esrc) {
    int i = blockIdx.x * blockDim.x + threadIdx.x;
    int stride = gridDim.x * blockDim.x;
    const int totalA = EA_N / 4;
    const int total = (EA_N + EG_N) / 4;
    for (; i < total; i += stride) {
        int4 d, s;
        int base;
        if (i < totalA) {
            d = a2b_dst4[i]; s = a2b_src4[i]; base = 0;
        } else {
            d = g2b_dst4[i - totalA]; s = g2b_src4[i - totalA]; base = NB;
        }
        int p0 = atomicAdd(&cursor[base + d.x], 1); esrc[p0] = s.x;
        int p1 = atomicAdd(&cursor[base + d.y], 1); esrc[p1] = s.y;
        int p2 = atomicAdd(&cursor[base + d.z], 1); esrc[p2] = s.z;
        int p3 = atomicAdd(&cursor[base + d.w], 1); esrc[p3] = s.w;
    }
}

// ---------------- fused mega kernel ----------------
// blocks [0, BOND_BLKS): 16 bonds/block, 16 lanes (float4) per bond.
// blocks [BOND_BLKS, +COPYA_BLKS): atom pass-through copy (nontemporal).
// remaining blocks: global pass-through copy (nontemporal).

__global__ __launch_bounds__(256) void mega_kernel(
    const float4* __restrict__ bond4, const float4* __restrict__ atom4,
    const float4* __restrict__ glob4, const int* __restrict__ offs,
    const int* __restrict__ esrc, float4* __restrict__ ft4,
    float4* __restrict__ out_atom4, float4* __restrict__ out_glob4) {
    int bid = blockIdx.x;

    if (bid < BOND_BLKS) {
        long long b = (long long)bid * 16 + (threadIdx.x >> 4);
        int q = threadIdx.x & 15;          // float4 slot within the row
        int gbase = threadIdx.x & 48;      // group base lane within the wave

        // ---- level 0: all offset loads issued together ----
        int a0 = offs[b], a1 = offs[b + 1];
        int g0 = offs[NB + b], g1 = offs[NB + b + 1];
        float4 bv = ntload4(&bond4[b * 16 + q]);

        int dega = a1 - a0;
        int degg = g1 - g0;

        // ---- level 1: both etypes' edge indices issued together ----
        int my_sa = (q < dega) ? esrc[a0 + q] : 0;
        int my_sg = (q < degg) ? esrc[g0 + q] : 0;

        // ---- level 2: gathers (independent within & across etypes) ----
        float4 sa = make_float4(0.f, 0.f, 0.f, 0.f);
        float4 xa = make_float4(-INFINITY, -INFINITY, -INFINITY, -INFINITY);
        int na = min(dega, 16);
        for (int j = 0; j < na; ++j) {
            int s = __shfl(my_sa, gbase + j, 64);
            float4 v = atom4[(long long)s * 16 + q];
            sa = f4add(sa, v);
            xa = f4max(xa, v);
        }
        for (int e = a0 + 16; e < a1; ++e) {    // rare tail (deg > 16)
            int s = esrc[e];
            float4 v = atom4[(long long)s * 16 + q];
            sa = f4add(sa, v);
            xa = f4max(xa, v);
        }

        float4 sg = make_float4(0.f, 0.f, 0.f, 0.f);
        float4 xg = make_float4(-INFINITY, -INFINITY, -INFINITY, -INFINITY);
        int ng = min(degg, 16);
        for (int j = 0; j < ng; ++j) {
            int s = __shfl(my_sg, gbase + j, 64);
            float4 v = glob4[(long long)s * 16 + q];
            sg = f4add(sg, v);
            xg = f4max(xg, v);
        }
        for (int e = g0 + 16; e < g1; ++e) {
            int s = esrc[e];
            float4 v = glob4[(long long)s * 16 + q];
            sg = f4add(sg, v);
            xg = f4max(xg, v);
        }

        float4 ma = f4scale(sa, dega ? 1.f / (float)dega : 0.f);
        if (!dega) xa = make_float4(0.f, 0.f, 0.f, 0.f);
        float4 mg = f4scale(sg, degg ? 1.f / (float)degg : 0.f);
        if (!degg) xg = make_float4(0.f, 0.f, 0.f, 0.f);

        // ---- write the 320-col row (nontemporal: written once, never read) ----
        float4* row = ft4 + b * 80;
        ntstore4(bv, &row[q]);
        ntstore4(ma, &row[16 + q]);
        ntstore4(xa, &row[32 + q]);
        ntstore4(mg, &row[48 + q]);
        ntstore4(xg, &row[64 + q]);
    } else if (bid < BOND_BLKS + COPYA_BLKS) {
        long long n4 = (long long)NA * DD / 4;
        long long i = (long long)(bid - BOND_BLKS) * 256 + threadIdx.x;
        long long stride = (long long)COPYA_BLKS * 256;
        for (; i < n4; i += stride) {
            float4 v = ntload4(&atom4[i]);
            ntstore4(v, &out_atom4[i]);
        }
    } else {
        long long n4 = (long long)NG * DD / 4;
        long long i = (long long)(bid - BOND_BLKS - COPYA_BLKS) * 256 + threadIdx.x;
        long long stride = (long long)COPYG_BLKS * 256;
        for (; i < n4; i += stride) {
            float4 v = ntload4(&glob4[i]);
            ntstore4(v, &out_glob4[i]);
        }
    }
}

// ---------------- launch ----------------

extern "C" void kernel_launch(void* const* d_in, const int* in_sizes, int n_in,
                              void* d_out, int out_size, void* d_ws, size_t ws_size,
                              hipStream_t stream) {
    const float* atom_ft   = (const float*)d_in[0];
    const float* bond_ft   = (const float*)d_in[1];
    const float* global_ft = (const float*)d_in[2];
    const int* a2b_src = (const int*)d_in[3];
    const int* a2b_dst = (const int*)d_in[4];
    const int* g2b_src = (const int*)d_in[5];
    const int* g2b_dst = (const int*)d_in[6];

    float* out = (float*)d_out;
    float* out_atom = out;                            // [NA,64]
    float* out_ft   = out + (long long)NA * DD;       // [NB,320]
    float* out_glob = out_ft + (long long)NB * FTC;   // [NG,64]

    int* ws      = (int*)d_ws;
    int* cnt     = ws;                   // NSEG
    int* offs    = ws + 1000000;         // NSEG+1
    int* cursor  = ws + 2000004;         // NSEG
    int* bsum    = ws + 3000004;         // SCAN_BLK
    int* esrc    = ws + 3001028;         // EA_N+EG_N

    const int BLK = 256;

    (void)hipMemsetAsync(cnt, 0, (size_t)NSEG * sizeof(int), stream);

    const int EDGE4_BLKS = ((EA_N + EG_N) / 4 + BLK - 1) / BLK;  // 1465
    count_kernel<<<EDGE4_BLKS, BLK, 0, stream>>>(
        (const int4*)a2b_dst, (const int4*)g2b_dst, cnt);

    scan1_kernel<<<NSCAN_BLKS, SCAN_BLK, 0, stream>>>(cnt, offs, bsum);
    scan2_kernel<<<1, SCAN_BLK, 0, stream>>>(bsum);
    scan3_kernel<<<NSCAN_BLKS, SCAN_BLK, 0, stream>>>(offs, bsum, cursor);

    fill_kernel<<<EDGE4_BLKS, BLK, 0, stream>>>(
        (const int4*)a2b_src, (const int4*)a2b_dst,
        (const int4*)g2b_src, (const int4*)g2b_dst, cursor, esrc);

    mega_kernel<<<BOND_BLKS + COPYA_BLKS + COPYG_BLKS, BLK, 0, stream>>>(
        (const float4*)bond_ft, (const float4*)atom_ft,
        (const float4*)global_ft, offs, esrc, (float4*)out_ft,
        (float4*)out_atom, (float4*)out_glob);
}